// Round 16
// baseline (542.154 us; speedup 1.0000x reference)
//
#include <hip/hip_runtime.h>

#define MDIM 8192   // B*S
#define KDIM 4096   // DIN
#define NDIM 11008  // DOUT

#define NBLK_W 1024

typedef float f32x4 __attribute__((ext_vector_type(4)));
typedef int   i32x4 __attribute__((ext_vector_type(4)));
typedef int   i32x16 __attribute__((ext_vector_type(16)));
typedef char  c4    __attribute__((ext_vector_type(4)));

#define GAS __attribute__((address_space(1)))
#define LAS __attribute__((address_space(3)))

// --- Kernel 1: sign(W) -> {-1,0,+1} i8, fused with |W| partial reduction ---
__global__ __launch_bounds__(256) void k_convert_w(const float* __restrict__ w,
                                                   char* __restrict__ wq,
                                                   float* __restrict__ partials) {
  const int n4 = (NDIM * KDIM) / 4;
  const int stride = gridDim.x * blockDim.x;
  float s = 0.f;
  for (int i = blockIdx.x * blockDim.x + threadIdx.x; i < n4; i += stride) {
    f32x4 v = ((const f32x4*)w)[i];
    s += fabsf(v.x) + fabsf(v.y) + fabsf(v.z) + fabsf(v.w);
    c4 q;
    q.x = v.x > 0.f ? 1 : (v.x < 0.f ? -1 : 0);
    q.y = v.y > 0.f ? 1 : (v.y < 0.f ? -1 : 0);
    q.z = v.z > 0.f ? 1 : (v.z < 0.f ? -1 : 0);
    q.w = v.w > 0.f ? 1 : (v.w < 0.f ? -1 : 0);
    ((c4*)wq)[i] = q;
  }
  #pragma unroll
  for (int off = 32; off > 0; off >>= 1) s += __shfl_down(s, off, 64);
  __shared__ float red[4];
  if ((threadIdx.x & 63) == 0) red[threadIdx.x >> 6] = s;
  __syncthreads();
  if (threadIdx.x == 0) partials[blockIdx.x] = red[0] + red[1] + red[2] + red[3];
}

// --- Kernel 2: deterministic final reduction -> scale_w = mean|W| ---
__global__ __launch_bounds__(256) void k_scale(const float* __restrict__ partials,
                                               float* __restrict__ scale) {
  float s = 0.f;
  for (int i = threadIdx.x; i < NBLK_W; i += 256) s += partials[i];
  #pragma unroll
  for (int off = 32; off > 0; off >>= 1) s += __shfl_down(s, off, 64);
  __shared__ float red[4];
  if ((threadIdx.x & 63) == 0) red[threadIdx.x >> 6] = s;
  __syncthreads();
  if (threadIdx.x == 0)
    *scale = (red[0] + red[1] + red[2] + red[3]) / (float)((size_t)NDIM * KDIM);
}

// --- Kernel 3: x fp32 -> i8 with per-row scale s_x[m] = max|x[m,:]|/127 ---
__global__ __launch_bounds__(256) void k_convert_x(const float* __restrict__ x,
                                                   char* __restrict__ xq,
                                                   float* __restrict__ sx) {
  const int row = blockIdx.x;
  const float* xr = x + (size_t)row * KDIM;
  const int t = (int)threadIdx.x;
  f32x4 v[4];
  float mx = 0.f;
  #pragma unroll
  for (int j = 0; j < 4; ++j) {
    v[j] = *(const f32x4*)(xr + j * 1024 + t * 4);
    mx = fmaxf(mx, fmaxf(fmaxf(fabsf(v[j].x), fabsf(v[j].y)),
                         fmaxf(fabsf(v[j].z), fabsf(v[j].w))));
  }
  #pragma unroll
  for (int off = 32; off > 0; off >>= 1) mx = fmaxf(mx, __shfl_xor(mx, off, 64));
  __shared__ float red[4];
  __shared__ float bmax;
  if ((t & 63) == 0) red[t >> 6] = mx;
  __syncthreads();
  if (t == 0) {
    float m2 = fmaxf(fmaxf(red[0], red[1]), fmaxf(red[2], red[3]));
    m2 = fmaxf(m2, 1e-20f);
    bmax = m2;
    sx[row] = m2 * (1.f / 127.f);
  }
  __syncthreads();
  const float r = 127.f / bmax;
  #pragma unroll
  for (int j = 0; j < 4; ++j) {
    int a = __float2int_rn(v[j].x * r), b = __float2int_rn(v[j].y * r);
    int c = __float2int_rn(v[j].z * r), d = __float2int_rn(v[j].w * r);
    a = a > 127 ? 127 : (a < -127 ? -127 : a);
    b = b > 127 ? 127 : (b < -127 ? -127 : b);
    c = c > 127 ? 127 : (c < -127 ? -127 : c);
    d = d > 127 ? 127 : (d < -127 ? -127 : d);
    c4 q; q.x = (char)a; q.y = (char)b; q.z = (char)c; q.w = (char)d;
    *(c4*)(xq + (size_t)row * KDIM + j * 1024 + t * 4) = q;
  }
}

// --- Kernel 4: 128x256 8-phase i8 GEMM, 32x32x32 MFMA, 2 blk/CU + supertiles ---
// C[m][n] = scale_w * sx[m] * (sum_k xq[m][k]*wq[n][k]) + bias[n]
// SINGLE CHANGE vs r15 (435us GEMM, pass): MFMA 16x16x64 -> 32x32x32 i8
// (4404 vs 3944 TOPS ubench, +11.7%, half the instructions). Schedule skeleton,
// stage slots, VM(0) ledger, LDS layout/bytes, supertile grid: all identical.
// Per wave 64x64 = 2x2 tiles of 32; per phase 2 MFMA (one (Mt,Nt), kk=0,1);
// acc[2][2] i32x16 = 64 AGPR; frags af[2]+bq0[2]+bq1[2] = 24 VGPR (i32x4 each).
// Frag layout (analogy of r13-verified 16x16 i8): row=lane&31,
//   k=(lane>>5)*16+[0..16) contiguous bytes -> 1 ds_read_b128/frag.
// C/D (m74/m101, dtype-indep): col=lane&31, row=(r&3)+8*(r>>2)+4*(lane>>5).
// SWIZZLE bank check (64B rows): quad = (4*row + ((2kk+hi)^((row>>1)&3))) mod 8
//   over 64 lanes (row 0..31 x hi 0..1) = exactly 8 accesses/quad for kk=0 AND
//   kk=1 -> conflict-free (same math that predicted r13's measured 0).
// Quadrants: g0/g4:(M0,N0) g1/g5:(M0,N1) g2/g6:(M1,N0) g3/g7:(M1,N1).
// Load map (1 ahead, r15 lifetimes): pre: af(M0,b0),bq0(N0,b0); g0: bq1(N1,b0);
//   g1: af(M1,b0); g3: af(M0,b1)+bq0(N0,b1); g4: bq1(N1,b1); g5: af(M1,b1);
//   g7: af(M0,b0')+bq0(N0,b0'). Stage slots: g0/g1 b1.B.h0/h1<-kA; g3 b0.A<-kB;
//   g4/g5 b0.B.h0/h1<-kB; g7 b1.A<-kC. VM(0)@g2/g6 (spill-safe).

#define BAR()  __builtin_amdgcn_s_barrier()
#define SB0()  __builtin_amdgcn_sched_barrier(0)
#define PRIO1() __builtin_amdgcn_s_setprio(1)
#define PRIO0() __builtin_amdgcn_s_setprio(0)
#define VM(N)  asm volatile("s_waitcnt vmcnt(" #N ")" ::: "memory")

// One 8KB half-tile: 128 rows x 64 B; GROWB = global row base of the 128 rows
#define STAGE(GP, GROWB, LDSBASE, KT) do {                                            \
  const char* _s = (GP) + (size_t)((GROWB) + srow) * KDIM + (KT)*64 + scol;           \
  char* _d = lds + (LDSBASE) + tid*16;                                                \
  __builtin_amdgcn_global_load_lds((const GAS unsigned int*)_s,                       \
                                   (LAS unsigned int*)_d, 16, 0, 0);                  \
} while (0)

// B frags for one 32-col Ntile: DST[kk], kk = K-step of 32
#define LOAD_B1(DST, BUF, NT)                                                         \
  _Pragma("unroll") for (int kk = 0; kk < 2; ++kk)                                    \
    DST[kk] = *(const i32x4*)&lds[(BUF)*24576 + 8192 + bWOff + (NT)*2048              \
                                  + rowoff + rcol[kk]];

// A frags for one 32-row Mtile of this wave's 64 rows
#define LOAD_A1(DST, BUF, MT)                                                         \
  _Pragma("unroll") for (int kk = 0; kk < 2; ++kk)                                    \
    DST[kk] = *(const i32x4*)&lds[(BUF)*24576 + aWOff + (MT)*2048                     \
                                  + rowoff + rcol[kk]];

// 2 MFMA (32x32x32 i8) over kk -> acc[MI][NI]
#define MFMA2(AF, BQ, MI, NI)                                                         \
  _Pragma("unroll") for (int kk = 0; kk < 2; ++kk)                                    \
    acc[MI][NI] = __builtin_amdgcn_mfma_i32_32x32x32_i8(                              \
        AF[kk], BQ[kk], acc[MI][NI], 0, 0, 0);

__global__ __launch_bounds__(512, 4) void k_gemm256(const char* __restrict__ A,
                                                    const char* __restrict__ B,
                                                    const float* __restrict__ bias,
                                                    const float* __restrict__ sx,
                                                    const float* __restrict__ scale_p,
                                                    float* __restrict__ C) {
  extern __shared__ char lds[];

  const int nTn = NDIM / 256;                  // 43
  const int nwg = (MDIM / 128) * nTn;          // 2752 (== 0 mod 8)
  int wg = (int)blockIdx.x;
  wg = (wg & 7) * (nwg / 8) + (wg >> 3);       // XCD-aware swizzle (bijective)
  // 8x8 super-tile order within each XCD band (L2 panel reuse):
  const int band = wg / (nTn * 8);             // 0..7
  const int rem  = wg % (nTn * 8);             // 0..343
  const int tn   = rem >> 3;                   // 0..42
  const int tm   = band * 8 + (rem & 7);       // 0..63

  const int tid  = (int)threadIdx.x;
  const int lane = tid & 63;
  const int wave = tid >> 6;                   // 0..7
  const int wm   = wave >> 2;                  // 0..1  (M)
  const int wn   = wave & 3;                   // 0..3  (N)
  const int l31  = lane & 31;

  // read-side: row = lane&31, byte col = (kk*32 + (lane>>5)*16) ^ (((row>>1)&3)<<4)
  const int rowoff = l31 * 64;
  const int rsw = ((l31 >> 1) & 3) << 4;
  const int hi16 = (lane >> 5) << 4;
  int rcol[2];
  rcol[0] = hi16 ^ rsw;
  rcol[1] = (32 + hi16) ^ rsw;
  // stage-side (r13-verified involution): linear LDS dest; pre-swizzled src col
  const int srow = tid >> 2;                   // 0..127
  const int scol = ((tid & 3) << 4) ^ (((tid >> 3) & 3) << 4);

  const int aWOff = wm * 4096;                 // this wave's 64 A-rows (bytes)
  const int bWOff = wn * 4096;                 // this wave's 64 B-rows (bytes)
  const int aRow = tm * 128;
  const int bRow = tn * 256;

  i32x16 acc[2][2];
  #pragma unroll
  for (int i = 0; i < 2; ++i)
    #pragma unroll
    for (int j = 0; j < 2; ++j)
      #pragma unroll
      for (int e = 0; e < 16; ++e) acc[i][j][e] = 0;

  i32x4 af[2], bq0[2], bq1[2];

  // ---- prologue: buf0{A,B.h0,B.h1}<-K0; buf1.A<-K1; drain; preload g0 ----
  STAGE(A, aRow,        0,     0);
  STAGE(B, bRow,        8192,  0);
  STAGE(B, bRow + 128,  16384, 0);
  STAGE(A, aRow,        24576, 1);
  VM(0);
  SB0();
  BAR();
  LOAD_A1(af, 0, 0); LOAD_B1(bq0, 0, 0);       // operands for g0

  #pragma unroll 1
  for (int i = 0; i < 32; ++i) {
    const int kA = 2 * i + 1;                            // <= 63
    const int kB = (2 * i + 2 > 63) ? 63 : 2 * i + 2;    // clamped tail
    const int kC = (2 * i + 3 > 63) ? 63 : 2 * i + 3;
    // g0: MFMA(M0,N0)@b0; load bq1(N1,b0); stage b1.B.h0 <- kA
    PRIO1(); MFMA2(af, bq0, 0, 0); PRIO0(); SB0();
    LOAD_B1(bq1, 0, 1);
    STAGE(B, bRow,       32768, kA);
    BAR();
    // g1: MFMA(M0,N1); load af(M1,b0) (WAR-pinned after MFMA); stage b1.B.h1
    PRIO1(); MFMA2(af, bq1, 0, 1); PRIO0(); SB0();
    LOAD_A1(af, 0, 1);
    STAGE(B, bRow + 128, 40960, kA);
    BAR();
    // g2: MFMA(M1,N0); no loads/stage; VM(0) -> buf1 fully landed
    PRIO1(); MFMA2(af, bq0, 1, 0); PRIO0(); SB0();
    VM(0); SB0();
    BAR();
    // g3: MFMA(M1,N1); load af(M0,b1)+bq0(N0,b1); stage b0.A <- kB
    PRIO1(); MFMA2(af, bq1, 1, 1); PRIO0(); SB0();
    LOAD_A1(af, 1, 0); LOAD_B1(bq0, 1, 0);
    STAGE(A, aRow,       0,     kB);
    BAR();
    // g4: MFMA(M0,N0)@b1; load bq1(N1,b1); stage b0.B.h0 <- kB
    PRIO1(); MFMA2(af, bq0, 0, 0); PRIO0(); SB0();
    LOAD_B1(bq1, 1, 1);
    STAGE(B, bRow,       8192,  kB);
    BAR();
    // g5: MFMA(M0,N1); load af(M1,b1); stage b0.B.h1 <- kB
    PRIO1(); MFMA2(af, bq1, 0, 1); PRIO0(); SB0();
    LOAD_A1(af, 1, 1);
    STAGE(B, bRow + 128, 16384, kB);
    BAR();
    // g6: MFMA(M1,N0); no loads/stage; VM(0) -> buf0 fully landed
    PRIO1(); MFMA2(af, bq0, 1, 0); PRIO0(); SB0();
    VM(0); SB0();
    BAR();
    // g7: MFMA(M1,N1); load af(M0,b0')+bq0(N0,b0'); stage b1.A <- kC (next kA)
    PRIO1(); MFMA2(af, bq1, 1, 1); PRIO0(); SB0();
    LOAD_A1(af, 0, 0); LOAD_B1(bq0, 0, 0);
    STAGE(A, aRow,       24576, kC);
    BAR();
  }

  VM(0);  // drain the final g7 stage before epilogue

  const float sc = *scale_p;
  float bv[2];
  #pragma unroll
  for (int ni = 0; ni < 2; ++ni) bv[ni] = bias[tn * 256 + wn * 64 + ni * 32 + l31];

  // C/D layout (32x32, m74/m101): col = lane&31, row = (r&3)+8*(r>>2)+4*(lane>>5)
  #pragma unroll
  for (int mi = 0; mi < 2; ++mi) {
    #pragma unroll
    for (int r = 0; r < 16; ++r) {
      const int crow = (r & 3) + 8 * (r >> 2) + 4 * (lane >> 5);
      const int m = tm * 128 + wm * 64 + mi * 32 + crow;
      const float srow_scale = sc * sx[m];
      float* crowp = C + (size_t)m * NDIM + tn * 256 + wn * 64;
      #pragma unroll
      for (int ni = 0; ni < 2; ++ni)
        crowp[ni * 32 + l31] = srow_scale * (float)acc[mi][ni][r] + bv[ni];
    }
  }
}

extern "C" void kernel_launch(void* const* d_in, const int* in_sizes, int n_in,
                              void* d_out, int out_size, void* d_ws, size_t ws_size,
                              hipStream_t stream) {
  const float* x = (const float*)d_in[0];
  const float* w = (const float*)d_in[1];
  const float* bias = (const float*)d_in[2];
  float* out = (float*)d_out;

  char* ws = (char*)d_ws;
  const size_t XQ_BYTES = (size_t)MDIM * KDIM;   // 33,554,432
  const size_t WQ_BYTES = (size_t)NDIM * KDIM;   // 45,088,768
  char* xq = ws;
  char* wq = ws + XQ_BYTES;
  float* sx = (float*)(ws + XQ_BYTES + WQ_BYTES);
  float* partials = sx + MDIM;
  float* scale = partials + NBLK_W;

  k_convert_w<<<NBLK_W, 256, 0, stream>>>(w, wq, partials);
  k_scale<<<1, 256, 0, stream>>>(partials, scale);
  k_convert_x<<<MDIM, 256, 0, stream>>>(x, xq, sx);

  (void)hipFuncSetAttribute((const void*)k_gemm256,
                            hipFuncAttributeMaxDynamicSharedMemorySize, 49152);
  const int grid = (MDIM / 128) * (NDIM / 256);  // 2752
  k_gemm256<<<grid, 512, 49152, stream>>>(xq, wq, bias, sx, scale, out);
}

// Round 17
// 503.107 us; speedup vs baseline: 1.0776x; 1.0776x over previous
//
#include <hip/hip_runtime.h>

#define MDIM 8192   // B*S
#define KDIM 4096   // DIN
#define NDIM 11008  // DOUT

#define NBLK_W 1024

typedef float f32x4 __attribute__((ext_vector_type(4)));
typedef int   i32x4 __attribute__((ext_vector_type(4)));
typedef char  c4    __attribute__((ext_vector_type(4)));

#define GAS __attribute__((address_space(1)))
#define LAS __attribute__((address_space(3)))

// --- Kernel 1: sign(W) -> {-1,0,+1} i8, fused with |W| partial reduction ---
__global__ __launch_bounds__(256) void k_convert_w(const float* __restrict__ w,
                                                   char* __restrict__ wq,
                                                   float* __restrict__ partials) {
  const int n4 = (NDIM * KDIM) / 4;
  const int stride = gridDim.x * blockDim.x;
  float s = 0.f;
  for (int i = blockIdx.x * blockDim.x + threadIdx.x; i < n4; i += stride) {
    f32x4 v = ((const f32x4*)w)[i];
    s += fabsf(v.x) + fabsf(v.y) + fabsf(v.z) + fabsf(v.w);
    c4 q;
    q.x = v.x > 0.f ? 1 : (v.x < 0.f ? -1 : 0);
    q.y = v.y > 0.f ? 1 : (v.y < 0.f ? -1 : 0);
    q.z = v.z > 0.f ? 1 : (v.z < 0.f ? -1 : 0);
    q.w = v.w > 0.f ? 1 : (v.w < 0.f ? -1 : 0);
    ((c4*)wq)[i] = q;
  }
  #pragma unroll
  for (int off = 32; off > 0; off >>= 1) s += __shfl_down(s, off, 64);
  __shared__ float red[4];
  if ((threadIdx.x & 63) == 0) red[threadIdx.x >> 6] = s;
  __syncthreads();
  if (threadIdx.x == 0) partials[blockIdx.x] = red[0] + red[1] + red[2] + red[3];
}

// --- Kernel 2: deterministic final reduction -> scale_w = mean|W| ---
__global__ __launch_bounds__(256) void k_scale(const float* __restrict__ partials,
                                               float* __restrict__ scale) {
  float s = 0.f;
  for (int i = threadIdx.x; i < NBLK_W; i += 256) s += partials[i];
  #pragma unroll
  for (int off = 32; off > 0; off >>= 1) s += __shfl_down(s, off, 64);
  __shared__ float red[4];
  if ((threadIdx.x & 63) == 0) red[threadIdx.x >> 6] = s;
  __syncthreads();
  if (threadIdx.x == 0)
    *scale = (red[0] + red[1] + red[2] + red[3]) / (float)((size_t)NDIM * KDIM);
}

// --- Kernel 3: x fp32 -> i8 with per-row scale s_x[m] = max|x[m,:]|/127 ---
__global__ __launch_bounds__(256) void k_convert_x(const float* __restrict__ x,
                                                   char* __restrict__ xq,
                                                   float* __restrict__ sx) {
  const int row = blockIdx.x;
  const float* xr = x + (size_t)row * KDIM;
  const int t = (int)threadIdx.x;
  f32x4 v[4];
  float mx = 0.f;
  #pragma unroll
  for (int j = 0; j < 4; ++j) {
    v[j] = *(const f32x4*)(xr + j * 1024 + t * 4);
    mx = fmaxf(mx, fmaxf(fmaxf(fabsf(v[j].x), fabsf(v[j].y)),
                         fmaxf(fabsf(v[j].z), fabsf(v[j].w))));
  }
  #pragma unroll
  for (int off = 32; off > 0; off >>= 1) mx = fmaxf(mx, __shfl_xor(mx, off, 64));
  __shared__ float red[4];
  __shared__ float bmax;
  if ((t & 63) == 0) red[t >> 6] = mx;
  __syncthreads();
  if (t == 0) {
    float m2 = fmaxf(fmaxf(red[0], red[1]), fmaxf(red[2], red[3]));
    m2 = fmaxf(m2, 1e-20f);
    bmax = m2;
    sx[row] = m2 * (1.f / 127.f);
  }
  __syncthreads();
  const float r = 127.f / bmax;
  #pragma unroll
  for (int j = 0; j < 4; ++j) {
    int a = __float2int_rn(v[j].x * r), b = __float2int_rn(v[j].y * r);
    int c = __float2int_rn(v[j].z * r), d = __float2int_rn(v[j].w * r);
    a = a > 127 ? 127 : (a < -127 ? -127 : a);
    b = b > 127 ? 127 : (b < -127 ? -127 : b);
    c = c > 127 ? 127 : (c < -127 ? -127 : c);
    d = d > 127 ? 127 : (d < -127 ? -127 : d);
    c4 q; q.x = (char)a; q.y = (char)b; q.z = (char)c; q.w = (char)d;
    *(c4*)(xq + (size_t)row * KDIM + j * 1024 + t * 4) = q;
  }
}

// --- Kernel 4: 128x256 i8 GEMM (16x16x64), 2 blk/CU, TRIPLE-buffer deep ledger ---
// C[m][n] = scale_w * sx[m] * (sum_k xq[m][k]*wq[n][k]) + bias[n]
// vs r15 (435us GEMM, VM(0) drained 1-2-phase-old loads = inside HBM latency):
// 3 LDS buffers x 24KB (72KB/block, 2x72=144<=160 keeps 2 blk/CU). 4 phases per
// K-tile; while computing buffer j, stage buffer j+2 (A@p0, B.h0@p1, B.h1@p2);
// VM(3)@p2 retires buffer j+1's 3 loads at age 4-6 phases (1500-2300cyc >= HBM
// latency) -- never 0 in-loop (m201 property). Everything else = r15 byte-wise:
// 16x16x64 i8 MFMA (32x32 reverted: r16 bank-conflict 4.5e7), same frag layout
// + 3-bit swizzle (0 conflicts), supertile grid (FETCH 290MB), MFMA-first
// phases, 1 bar/phase, regs ~60+64acc.
// Buffer layout (24576B each): A:0..8191; B.h0:8192..16383; B.h1:16384..24575.
// Rotation: b_c (compute, K_i), b_n (next, K_i+1), b_s (stage tgt, K_i+2).
// Phases: p0: MFMA(L,01)@bc; load bq23(bc); stage A(bs)<-kS
//         p1: MFMA(L,23);    load afH(bc);  stage B.h0(bs)
//         p2: MFMA(H,01);    stage B.h1(bs); VM(3)
//         p3: MFMA(H,23);    load afL(bn)+bq01(bn)
// Ledger@p2-end: outstanding = bs{p0,p1,p2}(3) + bn{staged iter i-1}(3, ages
//   4-6 ph) -> VM(3) retires bn fully before p3's bn reads. Prologue stages
//   b0(3)+b1(3), VM(3) retires b0. WAR (checked per region): every overwrite
//   >= 3 barriers after its region's reads issued, >= 2 after consumption
//   (A(b_{i-1})@p0: afH read i-1.p1 consumed i-1.p2; B.h0@p1: bq01 read
//   i-2.p3 consumed i-1.p0; B.h1@p2: bq23 read i-1.p0 consumed i-1.p1).
// Tail: kS clamps to 63 -> idempotent dup-stage into never-again-read buffers;
//   ledger count exact. No other loop VMEM (frags 24 VGPR, spill-free).

#define BAR()  __builtin_amdgcn_s_barrier()
#define SB0()  __builtin_amdgcn_sched_barrier(0)
#define PRIO1() __builtin_amdgcn_s_setprio(1)
#define PRIO0() __builtin_amdgcn_s_setprio(0)
#define VM(N)  asm volatile("s_waitcnt vmcnt(" #N ")" ::: "memory")

// One 8KB half-tile: 128 rows x 64 B; GROWB = global row base; LDSOFF runtime
#define STAGE(GP, GROWB, LDSOFF, KT) do {                                             \
  const char* _s = (GP) + (size_t)((GROWB) + srow) * KDIM + (KT)*64 + scol;           \
  char* _d = lds + (LDSOFF) + tid*16;                                                 \
  __builtin_amdgcn_global_load_lds((const GAS unsigned int*)_s,                       \
                                   (LAS unsigned int*)_d, 16, 0, 0);                  \
} while (0)

// B frag pair: DST[ni] covers output cols wn*64 + NH*32 + ni*16 + l15
#define LOAD_B2(DST, BASE, NH)                                                        \
  _Pragma("unroll") for (int ni = 0; ni < 2; ++ni)                                    \
    DST[ni] = *(const i32x4*)&lds[(BASE) + 8192 + bWOff + (NH)*2048 + ni*1024         \
                                  + rowoff + rcol];

// A frag pair: DST[mi] covers output rows wm*64 + MH*32 + mi*16 + l15
#define LOAD_A2(DST, BASE, MH)                                                        \
  _Pragma("unroll") for (int mi = 0; mi < 2; ++mi)                                    \
    DST[mi] = *(const i32x4*)&lds[(BASE) + aWOff + (MH)*2048 + mi*1024                \
                                  + rowoff + rcol];

// 4 MFMA (16x16x64 i8): 2 mi x 2 ni -> acc[MB+mi][NB+ni]
#define MFMA4(AF, MB, BQ, NB)                                                         \
  _Pragma("unroll") for (int mi = 0; mi < 2; ++mi)                                    \
  _Pragma("unroll") for (int ni = 0; ni < 2; ++ni)                                    \
    acc[(MB)+mi][(NB)+ni] = __builtin_amdgcn_mfma_i32_16x16x64_i8(                    \
        AF[mi], BQ[ni], acc[(MB)+mi][(NB)+ni], 0, 0, 0);

__global__ __launch_bounds__(512, 4) void k_gemm256(const char* __restrict__ A,
                                                    const char* __restrict__ B,
                                                    const float* __restrict__ bias,
                                                    const float* __restrict__ sx,
                                                    const float* __restrict__ scale_p,
                                                    float* __restrict__ C) {
  extern __shared__ char lds[];

  const int nTn = NDIM / 256;                  // 43
  const int nwg = (MDIM / 128) * nTn;          // 2752 (== 0 mod 8)
  int wg = (int)blockIdx.x;
  wg = (wg & 7) * (nwg / 8) + (wg >> 3);       // XCD-aware swizzle (bijective)
  // 8x8 super-tile order within each XCD band (L2 panel reuse; FETCH 290MB r16)
  const int band = wg / (nTn * 8);             // 0..7
  const int rem  = wg % (nTn * 8);             // 0..343
  const int tn   = rem >> 3;                   // 0..42
  const int tm   = band * 8 + (rem & 7);       // 0..63

  const int tid  = (int)threadIdx.x;
  const int lane = tid & 63;
  const int wave = tid >> 6;                   // 0..7
  const int wm   = wave >> 2;                  // 0..1  (M)
  const int wn   = wave & 3;                   // 0..3  (N)
  const int l15  = lane & 15;

  // read-side (r13/r15-verified): row = l15 (+16-mults), byte col swizzled
  const int rowoff = l15 * 64;
  const int rcol = ((lane >> 4) << 4) ^ (((l15 >> 1) & 3) << 4);
  // stage-side (r13/r15-verified): linear LDS dest; pre-swizzled global src col
  const int srow = tid >> 2;                   // 0..127
  const int scol = ((tid & 3) << 4) ^ (((tid >> 3) & 3) << 4);

  const int aWOff = wm * 4096;                 // this wave's 64 A-rows (bytes)
  const int bWOff = wn * 4096;                 // this wave's 64 B-rows (bytes)
  const int aRow = tm * 128;
  const int bRow = tn * 256;

  i32x4 acc[4][4];
  #pragma unroll
  for (int i = 0; i < 4; ++i)
    #pragma unroll
    for (int j = 0; j < 4; ++j) acc[i][j] = i32x4{0, 0, 0, 0};

  i32x4 af[2], bq01[2], bq23[2];

  int b_c = 0, b_n = 24576, b_s = 49152;       // compute / next / stage bases

  // ---- prologue: b0{A,Bh0,Bh1}<-K0; b1{A,Bh0,Bh1}<-K1; VM(3) retires b0 ----
  STAGE(A, aRow,       0,             0);
  STAGE(B, bRow,       8192,          0);
  STAGE(B, bRow + 128, 16384,         0);
  STAGE(A, aRow,       24576,         1);
  STAGE(B, bRow,       24576 + 8192,  1);
  STAGE(B, bRow + 128, 24576 + 16384, 1);
  VM(3);
  SB0();
  BAR();
  LOAD_A2(af, 0, 0); LOAD_B2(bq01, 0, 0);      // operands for p0 (K0)

  #pragma unroll 1
  for (int i = 0; i < 64; ++i) {
    const int kS = (i + 2 > 63) ? 63 : i + 2;  // clamped tail (idempotent dup)
    // p0: MFMA(L,01)@bc; load bq23(bc); stage A(bs) <- kS
    PRIO1(); MFMA4(af, 0, bq01, 0); PRIO0(); SB0();
    LOAD_B2(bq23, b_c, 1);
    STAGE(A, aRow, b_s, kS);
    BAR();
    // p1: MFMA(L,23); load afH(bc) (WAR-pinned after MFMA); stage B.h0(bs)
    PRIO1(); MFMA4(af, 0, bq23, 2); PRIO0(); SB0();
    LOAD_A2(af, b_c, 1);
    STAGE(B, bRow, b_s + 8192, kS);
    BAR();
    // p2: MFMA(H,01); stage B.h1(bs); VM(3) retires b_n (ages 4-6 phases)
    PRIO1(); MFMA4(af, 2, bq01, 0); PRIO0(); SB0();
    STAGE(B, bRow + 128, b_s + 16384, kS);
    VM(3); SB0();
    BAR();
    // p3: MFMA(H,23); load afL(bn)+bq01(bn) for next iter's p0
    PRIO1(); MFMA4(af, 2, bq23, 2); PRIO0(); SB0();
    LOAD_A2(af, b_n, 0); LOAD_B2(bq01, b_n, 0);
    BAR();
    // rotate buffers
    const int t = b_c; b_c = b_n; b_n = b_s; b_s = t;
  }

  VM(0);  // drain tail dup-stages before epilogue

  const float sc = *scale_p;
  float bv[4];
  #pragma unroll
  for (int ni = 0; ni < 4; ++ni) bv[ni] = bias[tn * 256 + wn * 64 + ni * 16 + l15];

  // C/D layout (dtype-independent): col = lane&15, row = (lane>>4)*4 + reg
  #pragma unroll
  for (int mi = 0; mi < 4; ++mi) {
    #pragma unroll
    for (int r = 0; r < 4; ++r) {
      const int m = tm * 128 + wm * 64 + mi * 16 + (lane >> 4) * 4 + r;
      const float srow_scale = sc * sx[m];
      float* crow = C + (size_t)m * NDIM + tn * 256 + wn * 64;
      #pragma unroll
      for (int ni = 0; ni < 4; ++ni)
        crow[ni * 16 + l15] = srow_scale * (float)acc[mi][ni][r] + bv[ni];
    }
  }
}

extern "C" void kernel_launch(void* const* d_in, const int* in_sizes, int n_in,
                              void* d_out, int out_size, void* d_ws, size_t ws_size,
                              hipStream_t stream) {
  const float* x = (const float*)d_in[0];
  const float* w = (const float*)d_in[1];
  const float* bias = (const float*)d_in[2];
  float* out = (float*)d_out;

  char* ws = (char*)d_ws;
  const size_t XQ_BYTES = (size_t)MDIM * KDIM;   // 33,554,432
  const size_t WQ_BYTES = (size_t)NDIM * KDIM;   // 45,088,768
  char* xq = ws;
  char* wq = ws + XQ_BYTES;
  float* sx = (float*)(ws + XQ_BYTES + WQ_BYTES);
  float* partials = sx + MDIM;
  float* scale = partials + NBLK_W;

  k_convert_w<<<NBLK_W, 256, 0, stream>>>(w, wq, partials);
  k_scale<<<1, 256, 0, stream>>>(partials, scale);
  k_convert_x<<<MDIM, 256, 0, stream>>>(x, xq, sx);

  (void)hipFuncSetAttribute((const void*)k_gemm256,
                            hipFuncAttributeMaxDynamicSharedMemorySize, 73728);
  const int grid = (MDIM / 128) * (NDIM / 256);  // 2752
  k_gemm256<<<grid, 512, 73728, stream>>>(xq, wq, bias, sx, scale, out);
}